// Round 2
// baseline (406.490 us; speedup 1.0000x reference)
//
#include <hip/hip_runtime.h>

typedef __bf16 bf16_t;
typedef short s16x8 __attribute__((ext_vector_type(8)));   // MFMA A/B frag (8 bf16)
typedef __bf16 bf16x4 __attribute__((ext_vector_type(4)));
typedef float f32x4 __attribute__((ext_vector_type(4)));

#define BH   24
#define TT   2048
#define NN   256

// ---------------- Pass 1: RoPE(Q), RoPE(K) -> bf16 ----------------
__global__ __launch_bounds__(256) void rope_qk_kernel(
    const float* __restrict__ Q, const float* __restrict__ K,
    bf16_t* __restrict__ QR, bf16_t* __restrict__ KR)
{
    int gid = blockIdx.x * 256 + threadIdx.x;
    int idx = gid * 8;                      // flat element index, 8 elems (4 rope pairs)
    int n0 = idx & (NN - 1);
    int t  = (idx >> 8) & (TT - 1);

    float4 q0 = *(const float4*)(Q + idx);
    float4 q1 = *(const float4*)(Q + idx + 4);
    float4 k0 = *(const float4*)(K + idx);
    float4 k1 = *(const float4*)(K + idx + 4);
    float qv[8] = {q0.x, q0.y, q0.z, q0.w, q1.x, q1.y, q1.z, q1.w};
    float kv[8] = {k0.x, k0.y, k0.z, k0.w, k1.x, k1.y, k1.z, k1.w};

    bf16_t qo[8], ko[8];
    #pragma unroll
    for (int j = 0; j < 4; j++) {
        int n = n0 + 2 * j;                 // even index → q = n
        // freq = 2^(-16*n/256) / (2*pi)
        float freq = exp2f(-(float)n * 0.0625f) * 0.15915494309189535f;
        float ph = (float)t * freq;
        float r = ph - floorf(ph);          // revolutions in [0,1)
        float s = __builtin_amdgcn_sinf(r); // sin(2*pi*r)  (HW takes revolutions)
        float c = __builtin_amdgcn_cosf(r);
        qo[2*j]   = (bf16_t)(qv[2*j] * c - qv[2*j+1] * s);
        qo[2*j+1] = (bf16_t)(qv[2*j+1] * c + qv[2*j] * s);
        ko[2*j]   = (bf16_t)(kv[2*j] * c - kv[2*j+1] * s);
        ko[2*j+1] = (bf16_t)(kv[2*j+1] * c + kv[2*j] * s);
    }
    *(s16x8*)(QR + idx) = *(s16x8*)qo;
    *(s16x8*)(KR + idx) = *(s16x8*)ko;
}

// ---------------- Pass 2: V f32 [bh][t][n] -> Vt bf16 [bh][n][t] ----------------
__global__ __launch_bounds__(256) void vtrans_kernel(
    const float* __restrict__ V, bf16_t* __restrict__ Vt)
{
    __shared__ bf16_t tile[64][68];         // pad 68: breaks pow2 stride
    int bh = blockIdx.z;
    int t0 = blockIdx.x * 64;
    int n0 = blockIdx.y * 64;
    int rr = threadIdx.x >> 4;              // 0..15
    int c4 = (threadIdx.x & 15) * 4;        // 0..60

    const float* vb = V + ((long)bh * TT + t0) * NN + n0;
    #pragma unroll
    for (int i = 0; i < 4; i++) {
        int row = rr + i * 16;
        float4 v = *(const float4*)(vb + (long)row * NN + c4);
        bf16x4 b;
        b[0] = (bf16_t)v.x; b[1] = (bf16_t)v.y; b[2] = (bf16_t)v.z; b[3] = (bf16_t)v.w;
        *(bf16x4*)&tile[row][c4] = b;
    }
    __syncthreads();
    bf16_t* ob = Vt + ((long)bh * NN + n0) * TT + t0;
    #pragma unroll
    for (int i = 0; i < 4; i++) {
        int n = rr + i * 16;
        bf16x4 b;
        b[0] = tile[c4 + 0][n]; b[1] = tile[c4 + 1][n];
        b[2] = tile[c4 + 2][n]; b[3] = tile[c4 + 3][n];
        *(bf16x4*)(ob + (long)n * TT + c4) = b;
    }
}

// ---------------- Pass 3: strictly-causal linear attention ----------------
// BM=128 q-rows per block (4 waves x 32 rows), SB=32 s per tile.
__global__ __launch_bounds__(256, 2) void attn_kernel(
    const bf16_t* __restrict__ QR, const bf16_t* __restrict__ KR,
    const bf16_t* __restrict__ Vt, float* __restrict__ Out)
{
    __shared__ bf16_t kr_s[32][256];        // 16 KB, XOR-swizzled rows (512B)
    __shared__ bf16_t vt_s[256][40];        // 20 KB, padded rows
    __shared__ bf16_t s_s[4][32][40];       // 10 KB, per-wave S tile, padded rows

    int bh   = blockIdx.y;
    int qt   = 15 - (int)blockIdx.x;        // big tiles first (load balance)
    int t0   = qt * 128;
    int tid  = threadIdx.x;
    int wave = tid >> 6;
    int lane = tid & 63;
    int lrow = lane & 15;
    int lhi  = lane >> 4;
    int trow_base = t0 + wave * 32;

    // Q fragments in registers: 2 row-tiles x 8 k-blocks (A-frag: row=lane&15, k=lhi*8+j)
    s16x8 qfrag[2][8];
    #pragma unroll
    for (int rt = 0; rt < 2; rt++) {
        const bf16_t* qb = QR + ((long)bh * TT + trow_base + rt * 16 + lrow) * NN + lhi * 8;
        #pragma unroll
        for (int kb = 0; kb < 8; kb++)
            qfrag[rt][kb] = *(const s16x8*)(qb + kb * 32);
    }

    f32x4 zero4 = {0.0f, 0.0f, 0.0f, 0.0f};
    f32x4 oacc[2][16];
    #pragma unroll
    for (int rt = 0; rt < 2; rt++)
        #pragma unroll
        for (int nt = 0; nt < 16; nt++) oacc[rt][nt] = zero4;

    int krow  = tid >> 3;                   // 0..31
    int kcolb = (tid & 7) * 64;             // byte col base within row
    const bf16_t* krbase = KR + ((long)bh * TT + krow) * NN + (tid & 7) * 32;
    const bf16_t* vtbase = Vt + ((long)bh * NN + tid) * TT;

    int ns = (t0 + 128) >> 5;               // s-tiles: 4*qt+4
    for (int st = 0; st < ns; st++) {
        int s0 = st << 5;

        // stage KR tile [32][256] with XOR swizzle (byte ^= (row&7)<<4)
        {
            const bf16_t* src = krbase + (long)s0 * NN;
            char* dst = (char*)(&kr_s[0][0]) + krow * 512;
            #pragma unroll
            for (int c = 0; c < 4; c++) {
                s16x8 v = *(const s16x8*)(src + c * 8);
                *(s16x8*)(dst + ((kcolb + c * 16) ^ ((krow & 7) << 4))) = v;
            }
        }
        // stage Vt tile [256][32] (rows padded to 40)
        {
            const bf16_t* src = vtbase + s0;
            #pragma unroll
            for (int c = 0; c < 4; c++)
                *(s16x8*)(&vt_s[tid][c * 8]) = *(const s16x8*)(src + c * 8);
        }
        __syncthreads();

        if (s0 < trow_base + 32) {          // wave-uniform skip of fully-masked tiles
            // ---- QK^T: S[32 rows][32 s] per wave ----
            f32x4 sacc[2][2];
            sacc[0][0] = zero4; sacc[0][1] = zero4; sacc[1][0] = zero4; sacc[1][1] = zero4;
            #pragma unroll
            for (int kb = 0; kb < 8; kb++) {
                #pragma unroll
                for (int h2 = 0; h2 < 2; h2++) {
                    int srow = h2 * 16 + lrow;
                    s16x8 bfr = *(const s16x8*)((char*)(&kr_s[0][0]) + srow * 512 +
                                    ((kb * 64 + lhi * 16) ^ ((srow & 7) << 4)));
                    sacc[0][h2] = __builtin_amdgcn_mfma_f32_16x16x32_bf16(
                                      qfrag[0][kb], bfr, sacc[0][h2], 0, 0, 0);
                    sacc[1][h2] = __builtin_amdgcn_mfma_f32_16x16x32_bf16(
                                      qfrag[1][kb], bfr, sacc[1][h2], 0, 0, 0);
                }
            }
            // ---- strict causal mask + S -> LDS (bf16) ----
            // C/D layout: col = lane&15 (s), row = lhi*4 + reg (q)
            #pragma unroll
            for (int rt = 0; rt < 2; rt++)
                #pragma unroll
                for (int h2 = 0; h2 < 2; h2++)
                    #pragma unroll
                    for (int r = 0; r < 4; r++) {
                        int t_g = trow_base + rt * 16 + lhi * 4 + r;
                        int s_g = s0 + h2 * 16 + lrow;
                        float v = (s_g < t_g) ? sacc[rt][h2][r] : 0.0f;
                        s_s[wave][rt * 16 + lhi * 4 + r][h2 * 16 + lrow] = (bf16_t)v;
                    }
            // ---- PV: O[32][256] += S[32][32] @ V[32][256] ----
            s16x8 afr0 = *(const s16x8*)(&s_s[wave][lrow][lhi * 8]);
            s16x8 afr1 = *(const s16x8*)(&s_s[wave][16 + lrow][lhi * 8]);
            #pragma unroll
            for (int nt = 0; nt < 16; nt++) {
                s16x8 bfr = *(const s16x8*)(&vt_s[nt * 16 + lrow][lhi * 8]);
                oacc[0][nt] = __builtin_amdgcn_mfma_f32_16x16x32_bf16(afr0, bfr, oacc[0][nt], 0, 0, 0);
                oacc[1][nt] = __builtin_amdgcn_mfma_f32_16x16x32_bf16(afr1, bfr, oacc[1][nt], 0, 0, 0);
            }
        }
        __syncthreads();
    }

    // ---- epilogue: fp32 store ----
    #pragma unroll
    for (int rt = 0; rt < 2; rt++) {
        float* ob = Out + ((long)bh * TT + trow_base + rt * 16 + lhi * 4) * NN + lrow;
        #pragma unroll
        for (int nt = 0; nt < 16; nt++)
            #pragma unroll
            for (int r = 0; r < 4; r++)
                ob[(long)r * NN + nt * 16] = oacc[rt][nt][r];
    }
}

extern "C" void kernel_launch(void* const* d_in, const int* in_sizes, int n_in,
                              void* d_out, int out_size, void* d_ws, size_t ws_size,
                              hipStream_t stream) {
    const float* Q = (const float*)d_in[0];
    const float* K = (const float*)d_in[1];
    const float* V = (const float*)d_in[2];
    float* Out = (float*)d_out;

    const long TOT = (long)BH * TT * NN;    // 12,582,912 elements
    bf16_t* qr = (bf16_t*)d_ws;
    bf16_t* kr = qr + TOT;
    bf16_t* vt = kr + TOT;                  // total ws use: 3 * 25.2 MB = 75.5 MB

    rope_qk_kernel<<<dim3((int)(TOT / 8 / 256)), dim3(256), 0, stream>>>(Q, K, qr, kr);
    vtrans_kernel<<<dim3(TT / 64, NN / 64, BH), dim3(256), 0, stream>>>(V, vt);
    attn_kernel<<<dim3(TT / 128, BH), dim3(256), 0, stream>>>(qr, kr, vt, Out);
}

// Round 3
// 352.403 us; speedup vs baseline: 1.1535x; 1.1535x over previous
//
#include <hip/hip_runtime.h>

typedef __bf16 bf16_t;
typedef short s16x8 __attribute__((ext_vector_type(8)));   // MFMA A/B frag (8 bf16)
typedef __bf16 bf16x4 __attribute__((ext_vector_type(4)));
typedef float f32x4 __attribute__((ext_vector_type(4)));

#define BH   24
#define TT   2048
#define NN   256

// ---------------- Pass 0: zero rows t in [1024, 2048) (atomic-accumulated region) ----
__global__ __launch_bounds__(256) void zero_upper_kernel(float* __restrict__ Out)
{
    int gid = blockIdx.x * 256 + threadIdx.x;   // 24 * 65536 float4s
    int bh  = gid >> 16;
    int off = gid & 65535;
    float4* p = (float4*)(Out + (long)bh * (TT * NN) + 1024 * NN);
    p[off] = make_float4(0.f, 0.f, 0.f, 0.f);
}

// ---------------- Pass 1: RoPE(Q), RoPE(K) -> bf16 ----------------
__global__ __launch_bounds__(256) void rope_qk_kernel(
    const float* __restrict__ Q, const float* __restrict__ K,
    bf16_t* __restrict__ QR, bf16_t* __restrict__ KR)
{
    int gid = blockIdx.x * 256 + threadIdx.x;
    int idx = gid * 8;                      // flat element index, 8 elems (4 rope pairs)
    int n0 = idx & (NN - 1);
    int t  = (idx >> 8) & (TT - 1);

    float4 q0 = *(const float4*)(Q + idx);
    float4 q1 = *(const float4*)(Q + idx + 4);
    float4 k0 = *(const float4*)(K + idx);
    float4 k1 = *(const float4*)(K + idx + 4);
    float qv[8] = {q0.x, q0.y, q0.z, q0.w, q1.x, q1.y, q1.z, q1.w};
    float kv[8] = {k0.x, k0.y, k0.z, k0.w, k1.x, k1.y, k1.z, k1.w};

    bf16_t qo[8], ko[8];
    #pragma unroll
    for (int j = 0; j < 4; j++) {
        int n = n0 + 2 * j;                 // even index → q = n
        float freq = exp2f(-(float)n * 0.0625f) * 0.15915494309189535f;
        float ph = (float)t * freq;
        float r = ph - floorf(ph);          // revolutions in [0,1)
        float s = __builtin_amdgcn_sinf(r);
        float c = __builtin_amdgcn_cosf(r);
        qo[2*j]   = (bf16_t)(qv[2*j] * c - qv[2*j+1] * s);
        qo[2*j+1] = (bf16_t)(qv[2*j+1] * c + qv[2*j] * s);
        ko[2*j]   = (bf16_t)(kv[2*j] * c - kv[2*j+1] * s);
        ko[2*j+1] = (bf16_t)(kv[2*j+1] * c + kv[2*j] * s);
    }
    *(s16x8*)(QR + idx) = *(s16x8*)qo;
    *(s16x8*)(KR + idx) = *(s16x8*)ko;
}

// ---------------- Pass 2: V f32 [bh][t][n] -> Vt bf16 [bh][n][t] ----------------
__global__ __launch_bounds__(256) void vtrans_kernel(
    const float* __restrict__ V, bf16_t* __restrict__ Vt)
{
    __shared__ bf16_t tile[64][68];
    int bh = blockIdx.z;
    int t0 = blockIdx.x * 64;
    int n0 = blockIdx.y * 64;
    int rr = threadIdx.x >> 4;              // 0..15
    int c4 = (threadIdx.x & 15) * 4;        // 0..60

    const float* vb = V + ((long)bh * TT + t0) * NN + n0;
    #pragma unroll
    for (int i = 0; i < 4; i++) {
        int row = rr + i * 16;
        float4 v = *(const float4*)(vb + (long)row * NN + c4);
        bf16x4 b;
        b[0] = (bf16_t)v.x; b[1] = (bf16_t)v.y; b[2] = (bf16_t)v.z; b[3] = (bf16_t)v.w;
        *(bf16x4*)&tile[row][c4] = b;
    }
    __syncthreads();
    bf16_t* ob = Vt + ((long)bh * NN + n0) * TT + t0;
    #pragma unroll
    for (int i = 0; i < 4; i++) {
        int n = rr + i * 16;
        bf16x4 b;
        b[0] = tile[c4 + 0][n]; b[1] = tile[c4 + 1][n];
        b[2] = tile[c4 + 2][n]; b[3] = tile[c4 + 3][n];
        *(bf16x4*)(ob + (long)n * TT + c4) = b;
    }
}

// ---------------- Pass 3: strictly-causal linear attention (split-s) ----------------
// BM=64 q-rows per block (4 waves x 16 rows), SB=32 per s-tile, s-chunk=1024.
// blockIdx.x in [0,48): x<16  -> qt=16+x, chunk0 [0,1024)           (atomic)
//                       x<32  -> qt=47-x, chunk1 [1024, 64qt+64)    (atomic)
//                       else  -> qt=47-x (15..0), full [0, 64qt+64) (direct store)
__global__ __launch_bounds__(256, 3) void attn_kernel(
    const bf16_t* __restrict__ QR, const bf16_t* __restrict__ KR,
    const bf16_t* __restrict__ Vt, float* __restrict__ Out)
{
    __shared__ bf16_t kr_s[32 * 256];       // 16 KB, swizzled: see phys() below
    __shared__ bf16_t vt_s[256][40];        // 20 KB, 80B rows (16B aligned, 8-row bank sweep)
    __shared__ bf16_t s_s[4][16][40];       // 5 KB, per-wave S tile

    int bh = blockIdx.y;
    int x  = blockIdx.x;
    int qt    = (x < 16) ? (16 + x) : (47 - x);
    int chunk = (x >= 16 && x < 32) ? 1 : 0;
    bool doAtomic = (qt >= 16);
    int t0 = qt * 64;

    int tid  = threadIdx.x;
    int wave = tid >> 6;
    int lane = tid & 63;
    int lrow = lane & 15;
    int lhi  = lane >> 4;
    int trow = t0 + wave * 16;              // this wave's first q-row

    // Q fragments: 16 rows x 256 k  (A-frag: row=lane&15, k=lhi*8+j per kb)
    s16x8 qfrag[8];
    {
        const bf16_t* qb = QR + ((long)bh * TT + trow + lrow) * NN + lhi * 8;
        #pragma unroll
        for (int kb = 0; kb < 8; kb++)
            qfrag[kb] = *(const s16x8*)(qb + kb * 32);
    }

    f32x4 zero4 = {0.f, 0.f, 0.f, 0.f};
    f32x4 oacc[16];
    #pragma unroll
    for (int nt = 0; nt < 16; nt++) oacc[nt] = zero4;

    // staging addresses
    int krow = tid >> 3;                    // 0..31 (K row within tile)
    int kch  = tid & 7;                     // 0..7  (64B chunk within 512B row)
    const bf16_t* krsrc = KR + ((long)bh * TT + krow) * NN + kch * 32;
    char* krdst = (char*)kr_s + krow * 512 + ((kch << 4) ^ ((krow & 7) << 4));
    const bf16_t* vtsrc = Vt + ((long)bh * NN + tid) * TT;

    int s_lo = chunk ? 1024 : 0;
    int s_hi = chunk ? (t0 + 64) : min(t0 + 64, 1024);
    int st0 = s_lo >> 5, st1 = s_hi >> 5;

    for (int st = st0; st < st1; st++) {
        int s0 = st << 5;

        // stage KR tile [32 s][256 n], swizzled phys = row*512 + sub*128 + ((ch*16)^((row&7)*16))
        {
            const bf16_t* src = krsrc + (long)s0 * NN;
            #pragma unroll
            for (int i = 0; i < 4; i++)
                *(s16x8*)(krdst + i * 128) = *(const s16x8*)(src + i * 8);
        }
        // stage Vt tile [256 n][32 s]
        {
            const bf16_t* src = vtsrc + s0;
            #pragma unroll
            for (int c = 0; c < 4; c++)
                *(s16x8*)(&vt_s[tid][c * 8]) = *(const s16x8*)(src + c * 8);
        }
        __syncthreads();

        if (s0 < trow + 16) {               // wave-uniform: tile has any s < t
            // ---- QK^T: S[16 rows][32 s] ----
            f32x4 sacc[2];
            sacc[0] = zero4; sacc[1] = zero4;
            #pragma unroll
            for (int kb = 0; kb < 8; kb++) {
                #pragma unroll
                for (int h2 = 0; h2 < 2; h2++) {
                    int srow = h2 * 16 + lrow;
                    s16x8 bfr = *(const s16x8*)((char*)kr_s + srow * 512 + lhi * 128 +
                                    ((kb << 4) ^ ((srow & 7) << 4)));
                    sacc[h2] = __builtin_amdgcn_mfma_f32_16x16x32_bf16(
                                   qfrag[kb], bfr, sacc[h2], 0, 0, 0);
                }
            }
            // ---- causal mask (only if tile crosses diagonal) + S -> LDS bf16 ----
            // C/D: col = lane&15 (s), row = lhi*4 + r (q)
            if (s0 + 32 > trow) {
                #pragma unroll
                for (int h2 = 0; h2 < 2; h2++)
                    #pragma unroll
                    for (int r = 0; r < 4; r++) {
                        int t_g = trow + lhi * 4 + r;
                        int s_g = s0 + h2 * 16 + lrow;
                        float v = (s_g < t_g) ? sacc[h2][r] : 0.0f;
                        s_s[wave][lhi * 4 + r][h2 * 16 + lrow] = (bf16_t)v;
                    }
            } else {
                #pragma unroll
                for (int h2 = 0; h2 < 2; h2++)
                    #pragma unroll
                    for (int r = 0; r < 4; r++)
                        s_s[wave][lhi * 4 + r][h2 * 16 + lrow] = (bf16_t)sacc[h2][r];
            }
            // ---- PV: O[16][256] += S[16][32] @ V[32][256] ----
            s16x8 afr = *(const s16x8*)(&s_s[wave][lrow][lhi * 8]);
            #pragma unroll
            for (int nt = 0; nt < 16; nt++) {
                s16x8 bfr = *(const s16x8*)(&vt_s[nt * 16 + lrow][lhi * 8]);
                oacc[nt] = __builtin_amdgcn_mfma_f32_16x16x32_bf16(afr, bfr, oacc[nt], 0, 0, 0);
            }
        }
        __syncthreads();
    }

    // ---- epilogue ----
    float* ob = Out + ((long)bh * TT + trow + lhi * 4) * NN + lrow;
    if (doAtomic) {
        #pragma unroll
        for (int nt = 0; nt < 16; nt++)
            #pragma unroll
            for (int r = 0; r < 4; r++)
                atomicAdd(&ob[(long)r * NN + nt * 16], oacc[nt][r]);
    } else {
        #pragma unroll
        for (int nt = 0; nt < 16; nt++)
            #pragma unroll
            for (int r = 0; r < 4; r++)
                ob[(long)r * NN + nt * 16] = oacc[nt][r];
    }
}

extern "C" void kernel_launch(void* const* d_in, const int* in_sizes, int n_in,
                              void* d_out, int out_size, void* d_ws, size_t ws_size,
                              hipStream_t stream) {
    const float* Q = (const float*)d_in[0];
    const float* K = (const float*)d_in[1];
    const float* V = (const float*)d_in[2];
    float* Out = (float*)d_out;

    const long TOT = (long)BH * TT * NN;    // 12,582,912 elements
    bf16_t* qr = (bf16_t*)d_ws;
    bf16_t* kr = qr + TOT;
    bf16_t* vt = kr + TOT;                  // ws use: 75.5 MB

    zero_upper_kernel<<<dim3(BH * 256), dim3(256), 0, stream>>>(Out);
    rope_qk_kernel<<<dim3((int)(TOT / 8 / 256)), dim3(256), 0, stream>>>(Q, K, qr, kr);
    vtrans_kernel<<<dim3(TT / 64, NN / 64, BH), dim3(256), 0, stream>>>(V, vt);
    attn_kernel<<<dim3(48, BH), dim3(256), 0, stream>>>(qr, kr, vt, Out);
}

// Round 5
// 334.988 us; speedup vs baseline: 1.2134x; 1.0520x over previous
//
#include <hip/hip_runtime.h>

typedef __bf16 bf16_t;
typedef short s16x8 __attribute__((ext_vector_type(8)));   // MFMA A/B frag (8 bf16)
typedef __bf16 bf16x4 __attribute__((ext_vector_type(4)));
typedef float f32x4 __attribute__((ext_vector_type(4)));

#define BH 24
#define TT 2048
#define NN 256

// ---- fused RoPE + f32->bf16 + optional row-major store + optional transposed store ----
__global__ __launch_bounds__(256) void rope_trans_kernel(
    const float* __restrict__ src, bf16_t* __restrict__ dstRow,
    bf16_t* __restrict__ dstT, int doRope)
{
    __shared__ bf16_t tile[64][68];
    int bh = blockIdx.z, t0 = blockIdx.x * 64, n0 = blockIdx.y * 64;
    int rr = threadIdx.x >> 4, c4 = (threadIdx.x & 15) * 4;
    #pragma unroll
    for (int i = 0; i < 4; i++) {
        int row = rr + i * 16;
        int t = t0 + row;
        float4 v = *(const float4*)(src + ((long)bh * TT + t) * NN + n0 + c4);
        bf16x4 b;
        if (doRope) {
            float f0 = exp2f(-(float)(n0 + c4) * 0.0625f) * 0.15915494309189535f;
            float f1 = exp2f(-(float)(n0 + c4 + 2) * 0.0625f) * 0.15915494309189535f;
            float p0 = (float)t * f0; p0 -= floorf(p0);
            float p1 = (float)t * f1; p1 -= floorf(p1);
            float s0 = __builtin_amdgcn_sinf(p0), c0 = __builtin_amdgcn_cosf(p0);
            float s1 = __builtin_amdgcn_sinf(p1), c1 = __builtin_amdgcn_cosf(p1);
            b[0] = (bf16_t)(v.x * c0 - v.y * s0);
            b[1] = (bf16_t)(v.y * c0 + v.x * s0);
            b[2] = (bf16_t)(v.z * c1 - v.w * s1);
            b[3] = (bf16_t)(v.w * c1 + v.z * s1);
        } else {
            b[0] = (bf16_t)v.x; b[1] = (bf16_t)v.y; b[2] = (bf16_t)v.z; b[3] = (bf16_t)v.w;
        }
        *(bf16x4*)&tile[row][c4] = b;
        if (dstRow) *(bf16x4*)(dstRow + ((long)bh * TT + t) * NN + n0 + c4) = b;
    }
    if (dstT) {
        __syncthreads();
        #pragma unroll
        for (int i = 0; i < 4; i++) {
            int n = rr + i * 16;
            bf16x4 b;
            b[0] = tile[c4][n]; b[1] = tile[c4 + 1][n];
            b[2] = tile[c4 + 2][n]; b[3] = tile[c4 + 3][n];
            *(bf16x4*)(dstT + ((long)bh * NN + n0 + n) * TT + t0 + c4) = b;
        }
    }
}

// ---- chunked linear attention: O = QR*S + tril(QR*KR^T,-1)*V ; S += KR^T*V ----
// grid (16, BH): blockIdx.x -> seg = x&3 (T segment of 512), nt = x>>2 (n_v tile of 64)
// 4 waves: wave w owns q-rows [w*16,w*16+16) per chunk and state rows n_k [w*64,w*64+64)
__global__ __launch_bounds__(256, 2) void attn_kernel(
    const bf16_t* __restrict__ QR, const bf16_t* __restrict__ KR,
    const bf16_t* __restrict__ KRt, const bf16_t* __restrict__ Vt,
    float* __restrict__ Out)
{
    __shared__ bf16_t kr_s[64 * 256];   // 32 KB  [s 64][n 256], rows XOR-swizzled
    __shared__ bf16_t S_lds[64 * 256];  // 32 KB  [n_v 64][n_k 256] = S^T bf16 mirror, swizzled
    __shared__ bf16_t s_s[4][16][72];   // 9 KB   per-wave masked P tile

    int bh = blockIdx.y;
    int seg = blockIdx.x & 3;
    int nt  = blockIdx.x >> 2;
    int tid = threadIdx.x;
    int w = tid >> 6, lane = tid & 63, lrow = lane & 15, lhi = lane >> 4;

    const bf16_t* QRb  = QR  + (long)bh * TT * NN;
    const bf16_t* KRb  = KR  + (long)bh * TT * NN;
    const bf16_t* KRtb = KRt + (long)bh * NN * TT;
    const bf16_t* Vtb  = Vt  + (long)bh * NN * TT;

    f32x4 zero4 = {0.f, 0.f, 0.f, 0.f};
    f32x4 sacc[4][4];                   // state S[n_k = w*64+i*16+lhi*4+r][n_v = nt*64+j*16+lrow]
    #pragma unroll
    for (int i = 0; i < 4; i++)
        #pragma unroll
        for (int j = 0; j < 4; j++) sacc[i][j] = zero4;

    const bf16_t* kabase = KRtb + ((long)(w * 64 + lrow)) * TT + lhi * 8;
    const bf16_t* vbbase = Vtb  + ((long)(nt * 64 + lrow)) * TT + lhi * 8;

    // ---- prologue: S over s in [0, seg*512), pairwise-unrolled for MLP ----
    int send = seg * 512;
    for (int s0 = 0; s0 < send; s0 += 128) {
        s16x8 kaA[4][2], vbA[4][2], kaB[4][2], vbB[4][2];
        #pragma unroll
        for (int i = 0; i < 4; i++)
            #pragma unroll
            for (int k2 = 0; k2 < 2; k2++) {
                kaA[i][k2] = *(const s16x8*)(kabase + (long)i * 16 * TT + s0 + k2 * 32);
                kaB[i][k2] = *(const s16x8*)(kabase + (long)i * 16 * TT + s0 + 64 + k2 * 32);
            }
        #pragma unroll
        for (int j = 0; j < 4; j++)
            #pragma unroll
            for (int k2 = 0; k2 < 2; k2++) {
                vbA[j][k2] = *(const s16x8*)(vbbase + (long)j * 16 * TT + s0 + k2 * 32);
                vbB[j][k2] = *(const s16x8*)(vbbase + (long)j * 16 * TT + s0 + 64 + k2 * 32);
            }
        #pragma unroll
        for (int i = 0; i < 4; i++)
            #pragma unroll
            for (int j = 0; j < 4; j++)
                #pragma unroll
                for (int k2 = 0; k2 < 2; k2++) {
                    sacc[i][j] = __builtin_amdgcn_mfma_f32_16x16x32_bf16(kaA[i][k2], vbA[j][k2], sacc[i][j], 0, 0, 0);
                    sacc[i][j] = __builtin_amdgcn_mfma_f32_16x16x32_bf16(kaB[i][k2], vbB[j][k2], sacc[i][j], 0, 0, 0);
                }
    }

    // S^T bf16 mirror writer (wave writes its own n_k rows into all its n_v rows)
    auto writeS = [&]() {
        #pragma unroll
        for (int j = 0; j < 4; j++) {
            int rv = j * 16 + lrow;
            char* rowp = (char*)S_lds + rv * 512;
            int swz = (rv & 7) << 4;
            #pragma unroll
            for (int i = 0; i < 4; i++) {
                bf16x4 b;
                b[0] = (bf16_t)sacc[i][j][0]; b[1] = (bf16_t)sacc[i][j][1];
                b[2] = (bf16_t)sacc[i][j][2]; b[3] = (bf16_t)sacc[i][j][3];
                *(bf16x4*)(rowp + ((w * 128 + i * 32 + lhi * 8) ^ swz)) = b;
            }
        }
    };
    writeS();
    __syncthreads();

    int krow = tid >> 2, kcb = (tid & 3) * 16;      // KR staging coords
    const bf16_t* qbase = QRb + ((long)(w * 16 + lrow)) * NN + lhi * 8;

    for (int ch = 0; ch < 8; ch++) {
        int t0 = seg * 512 + ch * 64;

        // stage KR chunk [64][256] swizzled
        {
            const char* srow = (const char*)(KRb + (long)(t0 + krow) * NN);
            char* drow = (char*)kr_s + krow * 512;
            int swz = (krow & 7) << 4;
            #pragma unroll
            for (int c = 0; c < 8; c++) {
                int cb = kcb + c * 64;
                *(s16x8*)(drow + (cb ^ swz)) = *(const s16x8*)(srow + cb);
            }
        }
        __syncthreads();                            // (A) kr_s staged, S_lds from prev chunk valid

        // issue global frag loads (qa needed first; vb/ka consumed later -> stay in flight)
        s16x8 qa[8];
        const bf16_t* qp = qbase + (long)t0 * NN;
        #pragma unroll
        for (int kb = 0; kb < 8; kb++) qa[kb] = *(const s16x8*)(qp + kb * 32);
        s16x8 vb[4][2], ka[4][2];
        #pragma unroll
        for (int j = 0; j < 4; j++)
            #pragma unroll
            for (int k2 = 0; k2 < 2; k2++)
                vb[j][k2] = *(const s16x8*)(vbbase + (long)j * 16 * TT + t0 + k2 * 32);
        #pragma unroll
        for (int i = 0; i < 4; i++)
            #pragma unroll
            for (int k2 = 0; k2 < 2; k2++)
                ka[i][k2] = *(const s16x8*)(kabase + (long)i * 16 * TT + t0 + k2 * 32);

        // ---- Q*S (inter-chunk): oacc[j] over n_k = 256 ----
        f32x4 oacc[4];
        #pragma unroll
        for (int j = 0; j < 4; j++) oacc[j] = zero4;
        #pragma unroll
        for (int kb = 0; kb < 8; kb++) {
            #pragma unroll
            for (int j = 0; j < 4; j++) {
                int rv = j * 16 + lrow;
                s16x8 sb = *(const s16x8*)((const char*)S_lds + rv * 512 +
                               ((kb * 64 + lhi * 16) ^ ((rv & 7) << 4)));
                oacc[j] = __builtin_amdgcn_mfma_f32_16x16x32_bf16(qa[kb], sb, oacc[j], 0, 0, 0);
            }
        }
        __syncthreads();                            // (B) Q*S reads done -> S_lds writable

        // ---- P = tril(QR*KR^T,-1), only s-tiles h <= w ----
        f32x4 pacc[4];
        #pragma unroll
        for (int h = 0; h < 4; h++) {
            if (h > w) continue;
            pacc[h] = zero4;
            #pragma unroll
            for (int kb = 0; kb < 8; kb++) {
                int rs = h * 16 + lrow;
                s16x8 kf = *(const s16x8*)((const char*)kr_s + rs * 512 +
                               ((kb * 64 + lhi * 16) ^ ((rs & 7) << 4)));
                pacc[h] = __builtin_amdgcn_mfma_f32_16x16x32_bf16(qa[kb], kf, pacc[h], 0, 0, 0);
            }
        }
        // mask diag tile + write P -> s_s (bf16)
        #pragma unroll
        for (int h = 0; h < 4; h++) {
            if (h > w) continue;
            #pragma unroll
            for (int r = 0; r < 4; r++) {
                float v = pacc[h][r];
                if (h == w && lrow >= lhi * 4 + r) v = 0.0f;   // strict: s < t
                s_s[w][lhi * 4 + r][h * 16 + lrow] = (bf16_t)v;
            }
        }
        if (!(w & 1)) {                              // zero tile h=w+1 (covered by kb2 range)
            #pragma unroll
            for (int r = 0; r < 4; r++) s_s[w][lhi * 4 + r][(w + 1) * 16 + lrow] = (bf16_t)0.0f;
        }
        // ---- P*V (intra) ----
        int nkb2 = (w >> 1) + 1;
        #pragma unroll
        for (int k2 = 0; k2 < 2; k2++) {
            if (k2 >= nkb2) continue;
            s16x8 pa = *(const s16x8*)(&s_s[w][lrow][k2 * 32 + lhi * 8]);
            #pragma unroll
            for (int j = 0; j < 4; j++)
                oacc[j] = __builtin_amdgcn_mfma_f32_16x16x32_bf16(pa, vb[j][k2], oacc[j], 0, 0, 0);
        }
        // ---- state update S += KR^T * V (full chunk, unmasked) ----
        #pragma unroll
        for (int i = 0; i < 4; i++)
            #pragma unroll
            for (int j = 0; j < 4; j++)
                #pragma unroll
                for (int k2 = 0; k2 < 2; k2++)
                    sacc[i][j] = __builtin_amdgcn_mfma_f32_16x16x32_bf16(ka[i][k2], vb[j][k2], sacc[i][j], 0, 0, 0);
        writeS();
        // ---- store O (f32, disjoint rows/cols per block) ----
        float* ob = Out + (long)bh * TT * NN + (long)(t0 + w * 16 + lhi * 4) * NN + nt * 64 + lrow;
        #pragma unroll
        for (int j = 0; j < 4; j++)
            #pragma unroll
            for (int r = 0; r < 4; r++)
                ob[(long)r * NN + j * 16] = oacc[j][r];
        __syncthreads();                            // (C) S_lds update visible for next chunk
    }
}

extern "C" void kernel_launch(void* const* d_in, const int* in_sizes, int n_in,
                              void* d_out, int out_size, void* d_ws, size_t ws_size,
                              hipStream_t stream) {
    const float* Q = (const float*)d_in[0];
    const float* K = (const float*)d_in[1];
    const float* V = (const float*)d_in[2];
    float* Out = (float*)d_out;

    const long TOT = (long)BH * TT * NN;    // 12,582,912 elements
    bf16_t* qr  = (bf16_t*)d_ws;
    bf16_t* kr  = qr + TOT;
    bf16_t* krt = kr + TOT;
    bf16_t* vt  = krt + TOT;                // ws use: 4 * 25.2 MB = 100.7 MB

    dim3 tg(TT / 64, NN / 64, BH);
    rope_trans_kernel<<<tg, dim3(256), 0, stream>>>(Q, qr, nullptr, 1);
    rope_trans_kernel<<<tg, dim3(256), 0, stream>>>(K, kr, krt, 1);
    rope_trans_kernel<<<tg, dim3(256), 0, stream>>>(V, nullptr, vt, 0);
    attn_kernel<<<dim3(16, BH), dim3(256), 0, stream>>>(qr, kr, krt, vt, Out);
}